// Round 9
// baseline (383.038 us; speedup 1.0000x reference)
//
#include <hip/hip_runtime.h>
#include <hip/hip_bf16.h>

typedef __bf16 bf16;
typedef _Float16 half_t;
typedef bf16 bf16x8 __attribute__((ext_vector_type(8)));
typedef bf16 bf16x4 __attribute__((ext_vector_type(4)));
typedef float floatx4 __attribute__((ext_vector_type(4)));

#define B_ 32
#define N_ 196
#define H_ 8
#define D_ 1024
#define DK_ 128
#define BN_ (B_ * N_)   // 6272
#define BH_ (B_ * H_)   // 256
#define MPAD_ 6400      // padded M for 256-row GEMM tiles (25 * 256)
#define NPAD_ 224       // padded N for S rows / Vt cols
#define PSTRIDE_ 232    // LDS P-tile col stride (16B aligned, bank-spread)

#define KT_ 16          // K tiles (BK=64), 1024 = 16*64 exact

typedef __attribute__((address_space(3))) unsigned int lds_uint;
typedef const __attribute__((address_space(1))) unsigned int glb_uint;

__device__ __forceinline__ void async_copy16(const bf16* g, bf16* l) {
  __builtin_amdgcn_global_load_lds((glb_uint*)g, (lds_uint*)l, 16, 0, 0);
}

#define BARRIER() asm volatile("s_barrier" ::: "memory")
#define WAITV0() asm volatile("s_waitcnt vmcnt(0)" ::: "memory")

// ---------------------------------------------------------------------------
// Batched f32 -> bf16 convert: blockIdx.y selects which tensor (same size).
// ---------------------------------------------------------------------------
__global__ __launch_bounds__(256) void cvt3_kernel(const float* __restrict__ s0,
                                                   const float* __restrict__ s1,
                                                   const float* __restrict__ s2,
                                                   bf16* __restrict__ d0,
                                                   bf16* __restrict__ d1,
                                                   bf16* __restrict__ d2, int n4) {
  const int which = blockIdx.y;
  const float* s = (which == 0) ? s0 : (which == 1) ? s1 : s2;
  bf16* d = (which == 0) ? d0 : (which == 1) ? d1 : d2;
  int i = blockIdx.x * 256 + threadIdx.x;
  if (i >= n4) return;
  float4 v = ((const float4*)s)[i];
  bf16x4 o;
  o[0] = (bf16)v.x;
  o[1] = (bf16)v.y;
  o[2] = (bf16)v.z;
  o[3] = (bf16)v.w;
  *(bf16x4*)(d + (size_t)i * 4) = o;
}

__global__ __launch_bounds__(256) void cvt4_kernel(const float* __restrict__ s0,
                                                   const float* __restrict__ s1,
                                                   const float* __restrict__ s2,
                                                   const float* __restrict__ s3,
                                                   bf16* __restrict__ d0,
                                                   bf16* __restrict__ d1,
                                                   bf16* __restrict__ d2,
                                                   bf16* __restrict__ d3, int n4) {
  const int which = blockIdx.y;
  const float* s = (which == 0) ? s0 : (which == 1) ? s1 : (which == 2) ? s2 : s3;
  bf16* d = (which == 0) ? d0 : (which == 1) ? d1 : (which == 2) ? d2 : d3;
  int i = blockIdx.x * 256 + threadIdx.x;
  if (i >= n4) return;
  float4 v = ((const float4*)s)[i];
  bf16x4 o;
  o[0] = (bf16)v.x;
  o[1] = (bf16)v.y;
  o[2] = (bf16)v.z;
  o[3] = (bf16)v.w;
  *(bf16x4*)(d + (size_t)i * 4) = o;
}

// ---------------------------------------------------------------------------
// Geometry weights (LINEAR domain): S[b,h,n,m] = max(relu(geo . WG_w[h] + b), 1e-6)
// stored f16. softmax(log w + s) == w*exp(s)/sum(w*exp(s)), so attn multiplies.
// ---------------------------------------------------------------------------
__global__ __launch_bounds__(256) void geo_kernel(const float* __restrict__ box,
                                                  const float* __restrict__ WGw,
                                                  const float* __restrict__ WGb,
                                                  half_t* __restrict__ S) {
  __shared__ float4 wsh[128];
  if (threadIdx.x < 128) wsh[threadIdx.x] = ((const float4*)WGw)[threadIdx.x];
  __syncthreads();

  int tid = blockIdx.x * 256 + threadIdx.x;
  int b = tid / (N_ * N_);
  int rem = tid - b * (N_ * N_);
  int n = rem / N_;
  int m = rem - n * N_;

  float4 bn = ((const float4*)box)[b * N_ + n];
  float4 bm = ((const float4*)box)[b * N_ + m];
  float cxn = (bn.x + bn.z) * 0.5f, cyn = (bn.y + bn.w) * 0.5f;
  float wn = bn.z - bn.x + 1.0f, hn = bn.w - bn.y + 1.0f;
  float cxm = (bm.x + bm.z) * 0.5f, cym = (bm.y + bm.w) * 0.5f;
  float wm = bm.z - bm.x + 1.0f, hm = bm.w - bm.y + 1.0f;

  float pos[4];
  pos[0] = __logf(fmaxf(fabsf((cxn - cxm) / wn), 1e-3f));
  pos[1] = __logf(fmaxf(fabsf((cyn - cym) / hn), 1e-3f));
  pos[2] = __logf(wn / wm);
  pos[3] = __logf(hn / hm);

  const float dims[8] = {1.0f,          0.4216965034f, 0.1778279410f, 0.0749894209f,
                         0.0316227766f, 0.0133352143f, 0.0056234133f, 0.0023713737f};
  float feat[64];
#pragma unroll
  for (int p = 0; p < 4; p++) {
#pragma unroll
    for (int f = 0; f < 8; f++) {
      float a = 100.0f * pos[p] * dims[f];
      feat[p * 8 + f] = __sinf(a);
      feat[32 + p * 8 + f] = __cosf(a);
    }
  }
#pragma unroll
  for (int hh = 0; hh < 8; hh++) {
    float accv = WGb[hh];
#pragma unroll
    for (int g4 = 0; g4 < 16; g4++) {
      float4 wv = wsh[hh * 16 + g4];
      accv += feat[g4 * 4 + 0] * wv.x + feat[g4 * 4 + 1] * wv.y +
              feat[g4 * 4 + 2] * wv.z + feat[g4 * 4 + 3] * wv.w;
    }
    S[((size_t)((b * H_ + hh) * N_ + n)) * NPAD_ + m] = (half_t)fmaxf(accv, 1e-6f);
  }
}

// ---------------------------------------------------------------------------
// 8-wave NT GEMM: 256x256 tile, BK=64, 8 waves (2M x 4N), per-wave 128x64
// (64 MFMA : 24 ds_read_b128 = 2.67), dbuf LDS 128 KB (1 block/CU).
// Counted-wait-by-construction: the ENTIRE next tile's 8 prefetch loads are
// issued at the TOP of each tile, compute (4 x 16-MFMA clusters, B-frags
// held in regs) runs ~800+ cycles, then the boundary vmcnt(0) waits on
// loads issued a full tile ago -> nearly free.  One barrier per K-tile.
// Cross-wave safety: each wave drains its OWN vmcnt before the barrier,
// so after the barrier all waves' gload_lds writes are visible.
// M padded to MPAD_ (stores guarded row < BN_).
//
// VARIANT 0: QKV (blockIdx.z selects input/weight/bias; z<2 bf16 row-major,
//            z==2 writes Vt[(bh*DK+d)*NPAD+n]).  VARIANT 1: f32 row-major.
// ---------------------------------------------------------------------------
template <int VARIANT>
__global__ __launch_bounds__(512) void gemm8w(
    const bf16* __restrict__ A0, const bf16* __restrict__ A1, const bf16* __restrict__ A2,
    const bf16* __restrict__ W0, const bf16* __restrict__ W1, const bf16* __restrict__ W2,
    const float* __restrict__ b0, const float* __restrict__ b1, const float* __restrict__ b2,
    void* __restrict__ O0, void* __restrict__ O1, void* __restrict__ O2) {
  __shared__ bf16 As[2][256 * 64];   // 2 x 32 KB
  __shared__ bf16 Bs[2][256 * 64];   // 2 x 32 KB

  const int z = (VARIANT == 0) ? blockIdx.z : 0;
  const bf16* A = (z == 0) ? A0 : (z == 1) ? A1 : A2;
  const bf16* W = (z == 0) ? W0 : (z == 1) ? W1 : W2;
  const float* bias = (z == 0) ? b0 : (z == 1) ? b1 : b2;

  const int tid = threadIdx.x;
  const int lane = tid & 63;
  const int wid = tid >> 6;
  const int l16 = lane & 15;
  const int quad = lane >> 4;
  const int wm = wid >> 2;   // 0..1 (M half: 128 rows)
  const int wn = wid & 3;    // 0..3 (N quarter: 64 cols)

  const bf16* gA = A + (size_t)blockIdx.y * 256 * D_;
  const bf16* gB = W + (size_t)blockIdx.x * 256 * D_;

  // staging: unit u slot = u*512 + tid; row = u*64 + (tid>>3); phys 16B-slot
  // = tid&7 holds logical slot (tid&7)^(row&7) -> pre-swizzled global src
  // (rule #21: linear gload_lds dest + inverse-swz src + swz read).
  const int srow = tid >> 3;                 // 0..63
  const int lslot = (tid & 7) ^ (srow & 7);
  size_t sOff[4];
#pragma unroll
  for (int u = 0; u < 4; u++) sOff[u] = (size_t)(u * 64 + srow) * D_ + lslot * 8;

  // read offsets: frag(row, kslot) at row*64 + ((kk*4+quad)^(row&7))*8
  int arow[8], brow[4], kslot[2];
#pragma unroll
  for (int i = 0; i < 8; i++) arow[i] = (wm * 128 + i * 16 + l16) * 64;
#pragma unroll
  for (int j = 0; j < 4; j++) brow[j] = (wn * 64 + j * 16 + l16) * 64;
#pragma unroll
  for (int kk = 0; kk < 2; kk++) kslot[kk] = ((kk * 4 + quad) ^ (l16 & 7)) * 8;

  floatx4 acc[8][4];
#pragma unroll
  for (int i = 0; i < 8; i++)
#pragma unroll
    for (int j = 0; j < 4; j++)
#pragma unroll
      for (int r = 0; r < 4; r++) acc[i][j][r] = 0.0f;

  // ---- prologue: stage tile 0 into buffer 0 (the only true stall) ----
#pragma unroll
  for (int u = 0; u < 4; u++) {
    async_copy16(gA + sOff[u], &As[0][(u * 512 + tid) * 8]);
    async_copy16(gB + sOff[u], &Bs[0][(u * 512 + tid) * 8]);
  }
  WAITV0();
  BARRIER();

  // ---- main loop ----
  for (int kt = 0; kt < KT_; ++kt) {
    const int cur = kt & 1;
    const bool pf = (kt + 1 < KT_);
    // issue the ENTIRE next tile's prefetch first: max issue-to-wait slack
    if (pf) {
      const bf16* pa = gA + (kt + 1) * 64;
      const bf16* pb = gB + (kt + 1) * 64;
#pragma unroll
      for (int u = 0; u < 4; u++) {
        async_copy16(pa + sOff[u], &As[cur ^ 1][(u * 512 + tid) * 8]);
        async_copy16(pb + sOff[u], &Bs[cur ^ 1][(u * 512 + tid) * 8]);
      }
    }
    const bf16* Ab = As[cur];
    const bf16* Bb = Bs[cur];

    // B fragments once per tile, held in regs across all 4 phases
    bf16x8 bfv[4][2];
#pragma unroll
    for (int j = 0; j < 4; j++)
#pragma unroll
      for (int kk = 0; kk < 2; kk++) bfv[j][kk] = *(const bf16x8*)(Bb + brow[j] + kslot[kk]);

    // 4 phases: i-pair per phase, 16 MFMA each
#pragma unroll
    for (int p = 0; p < 4; p++) {
      bf16x8 af[2][2];
#pragma unroll
      for (int i2 = 0; i2 < 2; i2++)
#pragma unroll
        for (int kk = 0; kk < 2; kk++)
          af[i2][kk] = *(const bf16x8*)(Ab + arow[p * 2 + i2] + kslot[kk]);
      __builtin_amdgcn_s_setprio(1);
#pragma unroll
      for (int i2 = 0; i2 < 2; i2++)
#pragma unroll
        for (int j = 0; j < 4; j++)
#pragma unroll
          for (int kk = 0; kk < 2; kk++)
            acc[p * 2 + i2][j] = __builtin_amdgcn_mfma_f32_16x16x32_bf16(
                af[i2][kk], bfv[j][kk], acc[p * 2 + i2][j], 0, 0, 0);
      __builtin_amdgcn_s_setprio(0);
    }

    // boundary: wait on loads issued a full tile ago (cheap), then swap
    if (pf) {
      WAITV0();
      BARRIER();
    }
  }

  // ---- epilogue (stores guarded: M is padded) ----
  const int m0 = blockIdx.y * 256 + wm * 128;
  const int n0 = blockIdx.x * 256 + wn * 64;
#pragma unroll
  for (int j = 0; j < 4; j++) {
    const int col = n0 + j * 16 + l16;
    const float bv = bias[col];
#pragma unroll
    for (int i = 0; i < 8; i++) {
#pragma unroll
      for (int r = 0; r < 4; r++) {
        const int row = m0 + i * 16 + quad * 4 + r;
        if (row < BN_) {
          float v = acc[i][j][r] + bv;
          if (VARIANT == 1) {
            ((float*)O0)[(size_t)row * D_ + col] = v;
          } else if (z < 2) {
            bf16* Cout = z ? (bf16*)O1 : (bf16*)O0;
            Cout[(size_t)row * D_ + col] = (bf16)v;
          } else {
            int b = row / N_;
            int n = row - b * N_;
            int h = col >> 7;
            int d = col & (DK_ - 1);
            ((bf16*)O2)[((size_t)((b * H_ + h) * DK_ + d)) * NPAD_ + n] = (bf16)v;
          }
        }
      }
    }
  }
}

// ---------------------------------------------------------------------------
// Fused attention (round-8 version, unchanged): ONE BLOCK PER (b,h).
// ---------------------------------------------------------------------------
__global__ __launch_bounds__(256) void attn_kernel(const bf16* __restrict__ Q,
                                                   const bf16* __restrict__ Kmat,
                                                   const bf16* __restrict__ Vt,
                                                   const half_t* __restrict__ Sb,
                                                   bf16* __restrict__ AO) {
  __shared__ bf16 Ks[7 * 4096];            // 56 KB
  __shared__ bf16 Vs[7 * 4096];            // 56 KB
  __shared__ bf16 Pl[4 * 16 * PSTRIDE_];   // 29 KB

  const int bh = blockIdx.x;
  const int b = bh >> 3;
  const int h = bh & 7;
  const int tid = threadIdx.x;
  const int wave = tid >> 6;
  const int lane = tid & 63;
  const int l16 = lane & 15;
  const int quad = lane >> 4;

  size_t kSrc[2];
  int kDst[2];
#pragma unroll
  for (int u = 0; u < 2; u++) {
    const int slot = u * 256 + tid;
    const int srow = slot >> 4;
    const int scs = slot & 15;
    kSrc[u] = (size_t)(b * N_ + srow) * D_ + h * DK_ + (scs ^ (srow & 7)) * 8;
    kDst[u] = slot * 8;
  }
  size_t vSrc[2];
#pragma unroll
  for (int u = 0; u < 2; u++) {
    const int slot = u * 256 + tid;
    const int vrow = slot >> 2;
    const int vcs = slot & 3;
    vSrc[u] = (size_t)bh * DK_ * NPAD_ + (size_t)vrow * NPAD_ + (vcs ^ (vrow & 3)) * 8;
  }

#pragma unroll
  for (int jt = 0; jt < 7; ++jt) {
    const size_t koff = (size_t)(jt * 32) * D_;
#pragma unroll
    for (int u = 0; u < 2; u++) async_copy16(Kmat + kSrc[u] + koff, Ks + jt * 4096 + kDst[u]);
  }
#pragma unroll
  for (int t7 = 0; t7 < 7; ++t7) {
#pragma unroll
    for (int u = 0; u < 2; u++) async_copy16(Vt + vSrc[u] + t7 * 32, Vs + t7 * 4096 + kDst[u]);
  }
  WAITV0();
  BARRIER();

  const float scale = 0.08838834764831845f;  // 1/sqrt(128)
  const half_t* bbase = Sb + ((size_t)bh * N_) * NPAD_;
  bf16* pw = Pl + wave * 16 * PSTRIDE_;
  const bf16* pr = pw + l16 * PSTRIDE_ + quad * 8;

  for (int rt = 0; rt < 4; ++rt) {
    const int nrb = rt * 64 + wave * 16;

    const int na = nrb + l16;
    const bool nav = na < N_;
    const bf16* aptr = Q + ((size_t)(b * N_ + (nav ? na : 0))) * D_ + h * DK_ + quad * 8;
    bf16x8 afr[4];
#pragma unroll
    for (int kk = 0; kk < 4; kk++) {
      bf16x8 v = *(const bf16x8*)(aptr + kk * 32);
      if (!nav) {
#pragma unroll
        for (int e = 0; e < 8; e++) v[e] = (bf16)0.0f;
      }
      afr[kk] = v;
    }

    floatx4 S[14];
#pragma unroll
    for (int j = 0; j < 14; j++)
#pragma unroll
      for (int r = 0; r < 4; r++) S[j][r] = 0.0f;

#pragma unroll
    for (int jt = 0; jt < 7; ++jt) {
      const bf16* Kb = Ks + jt * 4096;
      __builtin_amdgcn_s_setprio(1);
#pragma unroll
      for (int jj = 0; jj < 2; jj++) {
        const int mloc = jj * 16 + l16;
#pragma unroll
        for (int kk = 0; kk < 4; kk++) {
          bf16x8 bb = *(const bf16x8*)(Kb + mloc * 128 + ((kk * 4 + quad) ^ (l16 & 7)) * 8);
          S[jt * 2 + jj] = __builtin_amdgcn_mfma_f32_16x16x32_bf16(afr[kk], bb, S[jt * 2 + jj], 0, 0, 0);
        }
      }
      __builtin_amdgcn_s_setprio(0);
    }

    float inv[4];
#pragma unroll
    for (int r = 0; r < 4; r++) {
      const int n = nrb + quad * 4 + r;
      const bool nv = n < N_;
      const size_t brow = (size_t)(nv ? n : 0) * NPAD_;
      float mx = -1e30f;
#pragma unroll
      for (int j = 0; j < 14; j++) {
        const int m = j * 16 + l16;
        float s = (nv && m < N_) ? S[j][r] * scale : -1e30f;
        S[j][r] = s;
        mx = fmaxf(mx, s);
      }
#pragma unroll
      for (int off = 1; off < 16; off <<= 1) mx = fmaxf(mx, __shfl_xor(mx, off, 64));
      float sum = 0.0f;
#pragma unroll
      for (int j = 0; j < 14; j++) {
        const int m = j * 16 + l16;
        float w = (m < N_) ? (float)bbase[brow + m] : 0.0f;
        float e = w * __expf(S[j][r] - mx);
        sum += e;
        pw[(quad * 4 + r) * PSTRIDE_ + m] = (bf16)e;
      }
#pragma unroll
      for (int off = 1; off < 16; off <<= 1) sum += __shfl_xor(sum, off, 64);
      inv[r] = 1.0f / sum;
    }

    floatx4 O[8];
#pragma unroll
    for (int j2 = 0; j2 < 8; j2++)
#pragma unroll
      for (int r = 0; r < 4; r++) O[j2][r] = 0.0f;

#pragma unroll
    for (int t7 = 0; t7 < 7; ++t7) {
      const bf16* Vb = Vs + t7 * 4096;
      bf16x8 a = *(const bf16x8*)(pr + t7 * 32);
      __builtin_amdgcn_s_setprio(1);
#pragma unroll
      for (int j2 = 0; j2 < 8; j2++) {
        bf16x8 bb = *(const bf16x8*)(Vb + (j2 * 16 + l16) * 32 + (quad ^ (l16 & 3)) * 8);
        O[j2] = __builtin_amdgcn_mfma_f32_16x16x32_bf16(a, bb, O[j2], 0, 0, 0);
      }
      __builtin_amdgcn_s_setprio(0);
    }

#pragma unroll
    for (int r = 0; r < 4; r++) {
      const int n = nrb + quad * 4 + r;
      if (n < N_) {
#pragma unroll
        for (int j2 = 0; j2 < 8; j2++) {
          AO[((size_t)(b * N_ + n)) * D_ + h * DK_ + j2 * 16 + l16] = (bf16)(O[j2][r] * inv[r]);
        }
      }
    }
  }
}

// ---------------------------------------------------------------------------
extern "C" void kernel_launch(void* const* d_in, const int* in_sizes, int n_in,
                              void* d_out, int out_size, void* d_ws, size_t ws_size,
                              hipStream_t stream) {
  const float* xq = (const float*)d_in[0];
  const float* xk = (const float*)d_in[1];
  const float* xv = (const float*)d_in[2];
  const float* box = (const float*)d_in[3];
  const float* Wq = (const float*)d_in[4];
  const float* bq = (const float*)d_in[5];
  const float* Wk = (const float*)d_in[6];
  const float* bk = (const float*)d_in[7];
  const float* Wv = (const float*)d_in[8];
  const float* bv = (const float*)d_in[9];
  const float* Wo = (const float*)d_in[10];
  const float* bo = (const float*)d_in[11];
  const float* WGw = (const float*)d_in[12];
  const float* WGb = (const float*)d_in[13];

  size_t off = 0;
  char* wsc = (char*)d_ws;
  auto alloc = [&](size_t bytes) -> void* {
    void* p = wsc + off;
    off += (bytes + 255) & ~(size_t)255;
    return p;
  };
  // A-side buffers padded to MPAD_ rows (garbage pad rows; GEMM stores guarded)
  bf16* xq_b = (bf16*)alloc((size_t)MPAD_ * D_ * 2);
  bf16* xk_b = (bf16*)alloc((size_t)MPAD_ * D_ * 2);
  bf16* xv_b = (bf16*)alloc((size_t)MPAD_ * D_ * 2);
  bf16* wq_b = (bf16*)alloc((size_t)D_ * D_ * 2);
  bf16* wk_b = (bf16*)alloc((size_t)D_ * D_ * 2);
  bf16* wv_b = (bf16*)alloc((size_t)D_ * D_ * 2);
  bf16* wo_b = (bf16*)alloc((size_t)D_ * D_ * 2);
  bf16* q_b = (bf16*)alloc((size_t)BN_ * D_ * 2);
  bf16* k_b = (bf16*)alloc((size_t)BN_ * D_ * 2);
  bf16* vt_b = (bf16*)alloc((size_t)BH_ * DK_ * NPAD_ * 2);
  bf16* ao_b = (bf16*)alloc((size_t)MPAD_ * D_ * 2);
  half_t* S = (half_t*)alloc((size_t)BH_ * N_ * NPAD_ * 2);

  const int n4x = BN_ * D_ / 4;
  const int n4w = D_ * D_ / 4;
  dim3 g3(n4x / 256, 3, 1);
  cvt3_kernel<<<g3, 256, 0, stream>>>(xq, xk, xv, xq_b, xk_b, xv_b, n4x);
  dim3 g4(n4w / 256, 4, 1);
  cvt4_kernel<<<g4, 256, 0, stream>>>(Wq, Wk, Wv, Wo, wq_b, wk_b, wv_b, wo_b, n4w);

  geo_kernel<<<(B_ * N_ * N_) / 256, 256, 0, stream>>>(box, WGw, WGb, S);

  // zero Vt so its pad columns (n in [196,224)) are 0, not poison
  hipMemsetAsync(vt_b, 0, (size_t)BH_ * DK_ * NPAD_ * 2, stream);

  dim3 gqkv(D_ / 256, MPAD_ / 256, 3);
  gemm8w<0><<<gqkv, 512, 0, stream>>>(xq_b, xk_b, xv_b, wq_b, wk_b, wv_b, bq, bk, bv,
                                      q_b, k_b, vt_b);

  attn_kernel<<<BH_, 256, 0, stream>>>(q_b, k_b, vt_b, S, ao_b);

  dim3 gout(D_ / 256, MPAD_ / 256, 1);
  gemm8w<1><<<gout, 512, 0, stream>>>(ao_b, nullptr, nullptr, wo_b, nullptr, nullptr,
                                      bo, nullptr, nullptr, d_out, nullptr, nullptr);
}

// Round 11
// 299.551 us; speedup vs baseline: 1.2787x; 1.2787x over previous
//
#include <hip/hip_runtime.h>
#include <hip/hip_bf16.h>

typedef __bf16 bf16;
typedef _Float16 half_t;
typedef bf16 bf16x8 __attribute__((ext_vector_type(8)));
typedef bf16 bf16x4 __attribute__((ext_vector_type(4)));
typedef float floatx4 __attribute__((ext_vector_type(4)));

#define B_ 32
#define N_ 196
#define H_ 8
#define D_ 1024
#define DK_ 128
#define BN_ (B_ * N_)   // 6272
#define BH_ (B_ * H_)   // 256
#define NPAD_ 224       // padded N for S rows / Vt cols
#define PSTRIDE_ 232    // LDS P-tile col stride (16B aligned, bank-spread)

#define KT_ 16          // K tiles (BK=64), 1024 = 16*64 exact

// prep_kernel block ranges
#define CVT3_END_ 18816      // 3 x 6272
#define CVT4_END_ 22912      // + 4 x 1024
#define GEO_END_ 27714       // + 4802  (32*196*196 / 256)
#define ZERO_END_ 31298      // + 3584  (256*128*224*2 / 16 / 256)

typedef __attribute__((address_space(3))) unsigned int lds_uint;
typedef const __attribute__((address_space(1))) unsigned int glb_uint;

__device__ __forceinline__ void async_copy16(const bf16* g, bf16* l) {
  __builtin_amdgcn_global_load_lds((glb_uint*)g, (lds_uint*)l, 16, 0, 0);
}

#define BARRIER() asm volatile("s_barrier" ::: "memory")
#define WAITV0() asm volatile("s_waitcnt vmcnt(0)" ::: "memory")

// ---------------------------------------------------------------------------
// Fused front matter: f32->bf16 converts (x3 inputs, x4 weights), geometry
// bias, and Vt pad-zeroing — ONE launch.  These are mutually independent;
// fusing removes 4 launch gaps and co-schedules BW-bound cvt with
// VALU/trans-bound geo (separate pipes overlap, m114).
// ---------------------------------------------------------------------------
__global__ __launch_bounds__(256) void prep_kernel(
    const float* __restrict__ xq, const float* __restrict__ xk,
    const float* __restrict__ xv, const float* __restrict__ Wq,
    const float* __restrict__ Wk, const float* __restrict__ Wv,
    const float* __restrict__ Wo, const float* __restrict__ box,
    const float* __restrict__ WGw, const float* __restrict__ WGb,
    bf16* __restrict__ xq_b, bf16* __restrict__ xk_b, bf16* __restrict__ xv_b,
    bf16* __restrict__ wq_b, bf16* __restrict__ wk_b, bf16* __restrict__ wv_b,
    bf16* __restrict__ wo_b, half_t* __restrict__ S, uint4* __restrict__ vtz) {
  __shared__ float4 wsh[128];
  const int blk = blockIdx.x;
  const int tid = threadIdx.x;

  if (blk < CVT3_END_) {
    // ---- input converts: 3 tensors of BN_ x D_ f32 -> bf16 ----
    const int which = blk / 6272;
    const float* s = (which == 0) ? xq : (which == 1) ? xk : xv;
    bf16* d = (which == 0) ? xq_b : (which == 1) ? xk_b : xv_b;
    const int i = (blk - which * 6272) * 256 + tid;
    float4 v = ((const float4*)s)[i];
    bf16x4 o;
    o[0] = (bf16)v.x;
    o[1] = (bf16)v.y;
    o[2] = (bf16)v.z;
    o[3] = (bf16)v.w;
    *(bf16x4*)(d + (size_t)i * 4) = o;
  } else if (blk < CVT4_END_) {
    // ---- weight converts: 4 tensors of D_ x D_ f32 -> bf16 ----
    const int idx = blk - CVT3_END_;
    const int which = idx >> 10;
    const float* s = (which == 0) ? Wq : (which == 1) ? Wk : (which == 2) ? Wv : Wo;
    bf16* d = (which == 0) ? wq_b : (which == 1) ? wk_b : (which == 2) ? wv_b : wo_b;
    const int i = (idx & 1023) * 256 + tid;
    float4 v = ((const float4*)s)[i];
    bf16x4 o;
    o[0] = (bf16)v.x;
    o[1] = (bf16)v.y;
    o[2] = (bf16)v.z;
    o[3] = (bf16)v.w;
    *(bf16x4*)(d + (size_t)i * 4) = o;
  } else if (blk < GEO_END_) {
    // ---- geometry weights (LINEAR domain, f16):
    // S[b,h,n,m] = max(relu(geo(n,m) . WG_w[h] + b[h]), 1e-6)
    if (tid < 128) wsh[tid] = ((const float4*)WGw)[tid];
    __syncthreads();

    const int gid = (blk - CVT4_END_) * 256 + tid;
    const int b = gid / (N_ * N_);
    const int rem = gid - b * (N_ * N_);
    const int n = rem / N_;
    const int m = rem - n * N_;

    float4 bn = ((const float4*)box)[b * N_ + n];
    float4 bm = ((const float4*)box)[b * N_ + m];
    float cxn = (bn.x + bn.z) * 0.5f, cyn = (bn.y + bn.w) * 0.5f;
    float wn = bn.z - bn.x + 1.0f, hn = bn.w - bn.y + 1.0f;
    float cxm = (bm.x + bm.z) * 0.5f, cym = (bm.y + bm.w) * 0.5f;
    float wm = bm.z - bm.x + 1.0f, hm = bm.w - bm.y + 1.0f;

    float pos[4];
    pos[0] = __logf(fmaxf(fabsf((cxn - cxm) / wn), 1e-3f));
    pos[1] = __logf(fmaxf(fabsf((cyn - cym) / hn), 1e-3f));
    pos[2] = __logf(wn / wm);
    pos[3] = __logf(hn / hm);

    const float dims[8] = {1.0f,          0.4216965034f, 0.1778279410f, 0.0749894209f,
                           0.0316227766f, 0.0133352143f, 0.0056234133f, 0.0023713737f};
    float feat[64];
#pragma unroll
    for (int p = 0; p < 4; p++) {
#pragma unroll
      for (int ff = 0; ff < 8; ff++) {
        float a = 100.0f * pos[p] * dims[ff];
        feat[p * 8 + ff] = __sinf(a);
        feat[32 + p * 8 + ff] = __cosf(a);
      }
    }
#pragma unroll
    for (int hh = 0; hh < 8; hh++) {
      float accv = WGb[hh];
#pragma unroll
      for (int g4 = 0; g4 < 16; g4++) {
        float4 wv = wsh[hh * 16 + g4];
        accv += feat[g4 * 4 + 0] * wv.x + feat[g4 * 4 + 1] * wv.y +
                feat[g4 * 4 + 2] * wv.z + feat[g4 * 4 + 3] * wv.w;
      }
      S[((size_t)((b * H_ + hh) * N_ + n)) * NPAD_ + m] = (half_t)fmaxf(accv, 1e-6f);
    }
  } else {
    // ---- zero Vt (pad cols must be 0, not workspace poison) ----
    const int u = (blk - GEO_END_) * 256 + tid;
    vtz[u] = make_uint4(0u, 0u, 0u, 0u);
  }
}

// ---------------------------------------------------------------------------
// 2-phase NT GEMM (round-7 measured-best, UNCHANGED): 128x128 tile, BK=64,
// 4 waves, double-buffered LDS (2 blocks/CU), conflict-free XOR swizzle,
// setprio, XCD-chunked block swizzle (FETCH 155->48 MB verified round 7).
// ---------------------------------------------------------------------------
template <int VARIANT>
__global__ __launch_bounds__(256, 2) void gemm2p(
    const bf16* __restrict__ A0, const bf16* __restrict__ A1, const bf16* __restrict__ A2,
    const bf16* __restrict__ W0, const bf16* __restrict__ W1, const bf16* __restrict__ W2,
    const float* __restrict__ b0, const float* __restrict__ b1, const float* __restrict__ b2,
    void* __restrict__ O0, void* __restrict__ O1, void* __restrict__ O2) {
  __shared__ bf16 As[2][128 * 64];   // 2 x 16 KB
  __shared__ bf16 Bs[2][128 * 64];   // 2 x 16 KB

  // ---- XCD-chunked swizzle ----
  const int NZ = (VARIANT == 0) ? 3 : 1;
  const int chunk = 49 * NZ;
  const int f = blockIdx.x + (blockIdx.y << 3) + blockIdx.z * 392;
  const int L = (f & 7) * chunk + (f >> 3);
  const int lx = L & 7;                              // N-tile
  const int lyz = L >> 3;
  const int ly = (VARIANT == 0) ? (lyz % 49) : lyz;  // M-tile
  const int z = (VARIANT == 0) ? (lyz / 49) : 0;     // qkv select

  const bf16* A = (z == 0) ? A0 : (z == 1) ? A1 : A2;
  const bf16* W = (z == 0) ? W0 : (z == 1) ? W1 : W2;
  const float* bias = (z == 0) ? b0 : (z == 1) ? b1 : b2;

  const int tid = threadIdx.x;
  const int lane = tid & 63;
  const int wid = tid >> 6;
  const int l16 = lane & 15;
  const int quad = lane >> 4;
  const int wm = wid >> 1;
  const int wn = wid & 1;

  const bf16* gA = A + (size_t)ly * 128 * D_;
  const bf16* gB = W + (size_t)lx * 128 * D_;

  const int srow = tid >> 3;
  const int lslot = (tid & 7) ^ (srow & 7);
  size_t sOff[4];
#pragma unroll
  for (int u = 0; u < 4; u++) sOff[u] = (size_t)(u * 32 + srow) * D_ + lslot * 8;

  int arow[4], brow[4], kslot[2];
#pragma unroll
  for (int i = 0; i < 4; i++) arow[i] = (wm * 64 + i * 16 + l16) * 64;
#pragma unroll
  for (int j = 0; j < 4; j++) brow[j] = (wn * 64 + j * 16 + l16) * 64;
#pragma unroll
  for (int kk = 0; kk < 2; kk++) kslot[kk] = ((kk * 4 + quad) ^ (l16 & 7)) * 8;

  floatx4 acc[4][4];
#pragma unroll
  for (int i = 0; i < 4; i++)
#pragma unroll
    for (int j = 0; j < 4; j++)
#pragma unroll
      for (int r = 0; r < 4; r++) acc[i][j][r] = 0.0f;

#pragma unroll
  for (int u = 0; u < 4; u++) {
    async_copy16(gA + sOff[u], &As[0][u * 2048 + tid * 8]);
    async_copy16(gB + sOff[u], &Bs[0][u * 2048 + tid * 8]);
  }
  WAITV0();
  BARRIER();

  for (int kt = 0; kt < KT_; ++kt) {
    const int cur = kt & 1;
    const bf16* Ab = As[cur];
    const bf16* Bb = Bs[cur];
    const bool pf = (kt + 1 < KT_);
    const bf16* pa = gA + (kt + 1) * 64;
    const bf16* pb = gB + (kt + 1) * 64;
    bf16* dA = As[cur ^ 1];
    bf16* dB = Bs[cur ^ 1];
    bf16x8 af[4], bfv[4];

#pragma unroll
    for (int i = 0; i < 4; i++) af[i] = *(const bf16x8*)(Ab + arow[i] + kslot[0]);
#pragma unroll
    for (int j = 0; j < 4; j++) bfv[j] = *(const bf16x8*)(Bb + brow[j] + kslot[0]);
    if (pf) {
#pragma unroll
      for (int u = 0; u < 4; u++) async_copy16(pa + sOff[u], dA + u * 2048 + tid * 8);
    }
    __builtin_amdgcn_s_setprio(1);
#pragma unroll
    for (int i = 0; i < 4; i++)
#pragma unroll
      for (int j = 0; j < 4; j++)
        acc[i][j] = __builtin_amdgcn_mfma_f32_16x16x32_bf16(af[i], bfv[j], acc[i][j], 0, 0, 0);
    __builtin_amdgcn_s_setprio(0);

#pragma unroll
    for (int i = 0; i < 4; i++) af[i] = *(const bf16x8*)(Ab + arow[i] + kslot[1]);
#pragma unroll
    for (int j = 0; j < 4; j++) bfv[j] = *(const bf16x8*)(Bb + brow[j] + kslot[1]);
    if (pf) {
#pragma unroll
      for (int u = 0; u < 4; u++) async_copy16(pb + sOff[u], dB + u * 2048 + tid * 8);
    }
    __builtin_amdgcn_s_setprio(1);
#pragma unroll
    for (int i = 0; i < 4; i++)
#pragma unroll
      for (int j = 0; j < 4; j++)
        acc[i][j] = __builtin_amdgcn_mfma_f32_16x16x32_bf16(af[i], bfv[j], acc[i][j], 0, 0, 0);
    __builtin_amdgcn_s_setprio(0);

    if (pf) {
      WAITV0();
      BARRIER();
    }
  }

  const int m0 = ly * 128 + wm * 64;
  const int n0 = lx * 128 + wn * 64;
#pragma unroll
  for (int j = 0; j < 4; j++) {
    const int col = n0 + j * 16 + l16;
    const float bv = bias[col];
#pragma unroll
    for (int i = 0; i < 4; i++) {
#pragma unroll
      for (int r = 0; r < 4; r++) {
        const int row = m0 + i * 16 + quad * 4 + r;
        float v = acc[i][j][r] + bv;
        if (VARIANT == 1) {
          ((float*)O0)[(size_t)row * D_ + col] = v;
        } else if (z < 2) {
          bf16* Cout = z ? (bf16*)O1 : (bf16*)O0;
          Cout[(size_t)row * D_ + col] = (bf16)v;
        } else {
          int b = row / N_;
          int n = row - b * N_;
          int h = col >> 7;
          int d = col & (DK_ - 1);
          ((bf16*)O2)[((size_t)((b * H_ + h) * DK_ + d)) * NPAD_ + n] = (bf16)v;
        }
      }
    }
  }
}

// ---------------------------------------------------------------------------
// Fused attention (round-7 measured-best, UNCHANGED): per block = one (b,h)
// x 64 Q-rows; K/V staged into LDS (dbuf 32-row/32-col tiles, XOR swizzle);
// K-LDS unioned with the P-tile.
// ---------------------------------------------------------------------------
__global__ __launch_bounds__(256) void attn_kernel(const bf16* __restrict__ Q,
                                                   const bf16* __restrict__ Kmat,
                                                   const bf16* __restrict__ Vt,
                                                   const half_t* __restrict__ Sb,
                                                   bf16* __restrict__ AO) {
  __shared__ alignas(16) char smem[46080];
  bf16* KsB[2] = {(bf16*)smem, (bf16*)smem + 4096};
  bf16* Pl = (bf16*)smem;
  bf16* VsB[2] = {(bf16*)(smem + 29696), (bf16*)(smem + 29696) + 4096};

  const int f = blockIdx.x;
  const int tile = (f >> 3) & 3;
  const int bh = (f & 7) | ((f >> 5) << 3);      // tiles of one bh are 8 apart -> same XCD
  const int b = bh >> 3;
  const int h = bh & 7;
  const int tid = threadIdx.x;
  const int wave = tid >> 6;
  const int lane = tid & 63;
  const int l16 = lane & 15;
  const int quad = lane >> 4;
  const int nrb = tile * 64 + wave * 16;

  size_t kSrc[2];
  int kDst[2];
#pragma unroll
  for (int u = 0; u < 2; u++) {
    const int slot = u * 256 + tid;
    const int srow = slot >> 4;
    const int scs = slot & 15;
    kSrc[u] = (size_t)(b * N_ + srow) * D_ + h * DK_ + (scs ^ (srow & 7)) * 8;
    kDst[u] = slot * 8;
  }
  size_t vSrc[2];
#pragma unroll
  for (int u = 0; u < 2; u++) {
    const int slot = u * 256 + tid;
    const int vrow = slot >> 2;
    const int vcs = slot & 3;
    vSrc[u] = (size_t)bh * DK_ * NPAD_ + (size_t)vrow * NPAD_ + (vcs ^ (vrow & 3)) * 8;
  }

  // ---- prologue: stage K tile 0; load Q fragments ----
#pragma unroll
  for (int u = 0; u < 2; u++) async_copy16(Kmat + kSrc[u], KsB[0] + kDst[u]);

  const int na = nrb + l16;
  const bool nav = na < N_;
  const bf16* aptr = Q + ((size_t)(b * N_ + (nav ? na : 0))) * D_ + h * DK_ + quad * 8;
  bf16x8 afr[4];
#pragma unroll
  for (int kk = 0; kk < 4; kk++) {
    bf16x8 v = *(const bf16x8*)(aptr + kk * 32);
    if (!nav) {
#pragma unroll
      for (int e = 0; e < 8; e++) v[e] = (bf16)0.0f;
    }
    afr[kk] = v;
  }
  WAITV0();
  BARRIER();

  // ---- QK^T over 7 K-tiles of 32 rows (dbuf) ----
  floatx4 S[14];
#pragma unroll
  for (int j = 0; j < 14; j++)
#pragma unroll
    for (int r = 0; r < 4; r++) S[j][r] = 0.0f;

  for (int jt = 0; jt < 7; ++jt) {
    const int cur = jt & 1;
    if (jt < 6) {
      const size_t koff = (size_t)((jt + 1) * 32) * D_;
#pragma unroll
      for (int u = 0; u < 2; u++)
        async_copy16(Kmat + kSrc[u] + koff, KsB[cur ^ 1] + kDst[u]);
    }
    const bf16* Kb = KsB[cur];
    __builtin_amdgcn_s_setprio(1);
#pragma unroll
    for (int jj = 0; jj < 2; jj++) {
      const int mloc = jj * 16 + l16;
#pragma unroll
      for (int kk = 0; kk < 4; kk++) {
        bf16x8 bb = *(const bf16x8*)(Kb + mloc * 128 + ((kk * 4 + quad) ^ (l16 & 7)) * 8);
        S[jt * 2 + jj] = __builtin_amdgcn_mfma_f32_16x16x32_bf16(afr[kk], bb, S[jt * 2 + jj], 0, 0, 0);
      }
    }
    __builtin_amdgcn_s_setprio(0);
    if (jt < 6) {
      WAITV0();
      BARRIER();
    }
  }

  // early V-tile-0 stage (overlaps softmax; lands by the __syncthreads drain)
#pragma unroll
  for (int u = 0; u < 2; u++) async_copy16(Vt + vSrc[u], VsB[0] + kDst[u]);

  // all waves done reading Ks before Pl (same LDS region) is written
  BARRIER();

  // ---- scale + mask + max + weighted exp + P->LDS ----
  const float scale = 0.08838834764831845f;  // 1/sqrt(128)
  const half_t* bbase = Sb + ((size_t)bh * N_) * NPAD_;
  bf16* pw = Pl + wave * 16 * PSTRIDE_;
  float inv[4];
#pragma unroll
  for (int r = 0; r < 4; r++) {
    const int n = nrb + quad * 4 + r;
    const bool nv = n < N_;
    const size_t brow = (size_t)(nv ? n : 0) * NPAD_;
    float mx = -1e30f;
#pragma unroll
    for (int j = 0; j < 14; j++) {
      const int m = j * 16 + l16;
      float s = (nv && m < N_) ? S[j][r] * scale : -1e30f;
      S[j][r] = s;
      mx = fmaxf(mx, s);
    }
#pragma unroll
    for (int off = 1; off < 16; off <<= 1) mx = fmaxf(mx, __shfl_xor(mx, off, 64));
    float sum = 0.0f;
#pragma unroll
    for (int j = 0; j < 14; j++) {
      const int m = j * 16 + l16;
      float w = (m < N_) ? (float)bbase[brow + m] : 0.0f;
      float e = w * __expf(S[j][r] - mx);
      sum += e;
      pw[(quad * 4 + r) * PSTRIDE_ + m] = (bf16)e;
    }
#pragma unroll
    for (int off = 1; off < 16; off <<= 1) sum += __shfl_xor(sum, off, 64);
    inv[r] = 1.0f / sum;
  }
  __syncthreads();   // drains vmcnt too: V tile 0 landed, P visible

  // ---- PV over 7 n-tiles of 32 cols (dbuf) ----
  floatx4 O[8];
#pragma unroll
  for (int j2 = 0; j2 < 8; j2++)
#pragma unroll
    for (int r = 0; r < 4; r++) O[j2][r] = 0.0f;

  const bf16* pr = pw + l16 * PSTRIDE_ + quad * 8;
  for (int t7 = 0; t7 < 7; ++t7) {
    const int cur = t7 & 1;
    if (t7 < 6) {
      const size_t voff = (size_t)((t7 + 1) * 32);
#pragma unroll
      for (int u = 0; u < 2; u++)
        async_copy16(Vt + vSrc[u] + voff, VsB[cur ^ 1] + kDst[u]);
    }
    const bf16* Vb = VsB[cur];
    bf16x8 a = *(const bf16x8*)(pr + t7 * 32);
    __builtin_amdgcn_s_setprio(1);
#pragma unroll
    for (int j2 = 0; j2 < 8; j2++) {
      bf16x8 bb = *(const bf16x8*)(Vb + (j2 * 16 + l16) * 32 + (quad ^ (l16 & 3)) * 8);
      O[j2] = __builtin_amdgcn_mfma_f32_16x16x32_bf16(a, bb, O[j2], 0, 0, 0);
    }
    __builtin_amdgcn_s_setprio(0);
    if (t7 < 6) {
      WAITV0();
      BARRIER();
    }
  }

  // ---- epilogue: scale by 1/l, store ----
#pragma unroll
  for (int r = 0; r < 4; r++) {
    const int n = nrb + quad * 4 + r;
    if (n < N_) {
#pragma unroll
      for (int j2 = 0; j2 < 8; j2++) {
        AO[((size_t)(b * N_ + n)) * D_ + h * DK_ + j2 * 16 + l16] = (bf16)(O[j2][r] * inv[r]);
      }
    }
  }
}

// ---------------------------------------------------------------------------
extern "C" void kernel_launch(void* const* d_in, const int* in_sizes, int n_in,
                              void* d_out, int out_size, void* d_ws, size_t ws_size,
                              hipStream_t stream) {
  const float* xq = (const float*)d_in[0];
  const float* xk = (const float*)d_in[1];
  const float* xv = (const float*)d_in[2];
  const float* box = (const float*)d_in[3];
  const float* Wq = (const float*)d_in[4];
  const float* bq = (const float*)d_in[5];
  const float* Wk = (const float*)d_in[6];
  const float* bk = (const float*)d_in[7];
  const float* Wv = (const float*)d_in[8];
  const float* bv = (const float*)d_in[9];
  const float* Wo = (const float*)d_in[10];
  const float* bo = (const float*)d_in[11];
  const float* WGw = (const float*)d_in[12];
  const float* WGb = (const float*)d_in[13];

  size_t off = 0;
  char* wsc = (char*)d_ws;
  auto alloc = [&](size_t bytes) -> void* {
    void* p = wsc + off;
    off += (bytes + 255) & ~(size_t)255;
    return p;
  };
  bf16* xq_b = (bf16*)alloc((size_t)BN_ * D_ * 2);
  bf16* xk_b = (bf16*)alloc((size_t)BN_ * D_ * 2);
  bf16* xv_b = (bf16*)alloc((size_t)BN_ * D_ * 2);
  bf16* wq_b = (bf16*)alloc((size_t)D_ * D_ * 2);
  bf16* wk_b = (bf16*)alloc((size_t)D_ * D_ * 2);
  bf16* wv_b = (bf16*)alloc((size_t)D_ * D_ * 2);
  bf16* wo_b = (bf16*)alloc((size_t)D_ * D_ * 2);
  bf16* q_b = (bf16*)alloc((size_t)BN_ * D_ * 2);
  bf16* k_b = (bf16*)alloc((size_t)BN_ * D_ * 2);
  bf16* vt_b = (bf16*)alloc((size_t)BH_ * DK_ * NPAD_ * 2);
  bf16* ao_b = (bf16*)alloc((size_t)BN_ * D_ * 2);
  half_t* S = (half_t*)alloc((size_t)BH_ * N_ * NPAD_ * 2);

  // fused front matter (converts + geo + Vt zero): ONE launch
  prep_kernel<<<ZERO_END_, 256, 0, stream>>>(
      xq, xk, xv, Wq, Wk, Wv, Wo, box, WGw, WGb,
      xq_b, xk_b, xv_b, wq_b, wk_b, wv_b, wo_b, S, (uint4*)vt_b);

  dim3 gqkv(D_ / 128, BN_ / 128, 3);
  gemm2p<0><<<gqkv, 256, 0, stream>>>(xq_b, xk_b, xv_b, wq_b, wk_b, wv_b, bq, bk, bv,
                                      q_b, k_b, vt_b);

  attn_kernel<<<1024, 256, 0, stream>>>(q_b, k_b, vt_b, S, ao_b);

  dim3 gout(D_ / 128, BN_ / 128, 1);
  gemm2p<1><<<gout, 256, 0, stream>>>(ao_b, nullptr, nullptr, wo_b, nullptr, nullptr,
                                      bo, nullptr, nullptr, d_out, nullptr, nullptr);
}